// Round 13
// baseline (593.949 us; speedup 1.0000x reference)
//
#include <hip/hip_runtime.h>
#include <hip/hip_bf16.h>
#include <math.h>

// GAT 2-layer inference on MI355X.
// R1: gemm1 lane=row + LDS tile.  R2: bucketed CSR; fused agg; gemm2 thread=row.
// R3: gemm1 MFMA bf16; bf16 gather tables.
// R4: agg lane-parallel weight precompute + readlane broadcast (VALU fix).
// R5: gemm1 32-row tile x 512thr (occupancy fix); detect/convert split.
// R6 (REVERTED): sliced XCD-pinned aggs -- 3x instruction overhead.
// R7: h2 rows padded to 128B; scatter fused into gemm1 grid.
// R8 (REVERTED): 196->782 buckets doubled staging write-amp.
// R9 (REVERTED): direct ticket scatter -- random global atomics+stores ~10x cost.
// R10 (NEUTRAL): bucket_cnt line padding.
// R11: scatter branch LDS counting-sort + coalesced flush (WRITE 62->39MB). [593.3]
// R12 (REVERTED): deg histogram via 3.2M random global atomics (+100MB HBM).
// R13: agg gather groups 4->8 wide (latency-bound gathers). [577.5us BEST]
// R14 (REVERTED): 16-wide groups (VGPR pressure) bundled with dsum hoist.
// R15 (NEUTRAL): agg2 dsum hoist alone -- kept (fewer instrs, no regression).
// R16: fused kernel 512thr/4blk -> 256thr/8blk per CU (GROWS 32->16, scatter
//      chunk 4096->2048). Same 32 waves/CU but 8 independent barrier domains
//      (vs 4): each __syncthreads parks 4 waves not 8, stage/compute phases
//      of 8 blocks interleave. Same mechanism as R5's 127->~50us win.

#define DEV __device__ __forceinline__

constexpr int N_NODES = 100000;
constexpr int N_EDGES = 3200000;
constexpr int F_IN    = 500;
constexpr int HEADS   = 8;
constexpr int HID     = 8;
constexpr int D1      = HEADS * HID;   // 64
constexpr int NC      = 41;
constexpr int NCP     = 64;            // padded h2 row stride (128B line-aligned)

// bucketed CSR build
constexpr int NB    = 196;     // buckets of 512 nodes (dst >> 9)
constexpr int BCAP  = 20480;   // staging capacity per bucket (avg 16327)
constexpr int CSTR  = 16;      // bucket_cnt stride in ints (64B line per counter)
constexpr int SEPT  = 8;       // edges per thread in scatter branch (256 thr)
constexpr int SCHUNK = 256 * SEPT;   // 2048 edges per scatter block
constexpr int SBLKS = (N_EDGES + SCHUNK - 1) / SCHUNK;   // 1563

// gemm1 MFMA tile (R16: 16-row tile, 256 thr, 8 blocks/CU)
constexpr int GROWS = 16;      // rows per block
constexpr int LROW  = 520;     // LDS row stride in bf16
constexpr int GBLKS = N_NODES / GROWS;   // 6250

// agg1 per-wave weight tile: 8 heads x 64 edges, stride 68 floats
constexpr int WSTR = 68;

typedef __attribute__((ext_vector_type(8))) short bf16x8;
typedef __attribute__((ext_vector_type(4))) float f32x4;

DEV float bf2f(unsigned short u) {
    return __uint_as_float(((unsigned int)u) << 16);
}
DEV unsigned short f2b(float f) {   // RNE f32 -> bf16 bits
    unsigned int u = __float_as_uint(f);
    unsigned int r = (u + 0x7FFFu + ((u >> 16) & 1u)) >> 16;
    return (unsigned short)r;
}
DEV float leaky(float e) { return e > 0.f ? e : 0.2f * e; }
DEV float readlane_f(float v, int l) {
    return __uint_as_float((unsigned int)__builtin_amdgcn_readlane((int)__float_as_uint(v), l));
}

// ---------------------------------------------------------------- detect (1 wave)
__global__ void k_detect(const void* xraw, const void* eraw, int* flags) {
    const int lane = threadIdx.x & 63;
    const unsigned short* xu = (const unsigned short*)xraw;
    unsigned short v = xu[2 * lane];
    int e = (v >> 7) & 0xFF;
    int valid = (e == 0 || (e >= 90 && e <= 150)) ? 1 : 0;
    unsigned long long vm = __ballot(valid);
    const unsigned int* eu = (const unsigned int*)eraw;
    unsigned long long zm = __ballot(eu[2 * lane + 1] == 0u);
    if (lane == 0) {
        flags[0] = (__popcll(vm) < 56) ? 1 : 0;   // x is f32
        flags[1] = (__popcll(zm) == 64) ? 1 : 0;  // edge_index is i64
    }
}

// ---------------------------------------------------------------- convert weights (parallel)
__global__ __launch_bounds__(256) void k_convert(const void* w1, const void* a1s, const void* a1d,
                                                 const void* w2, const void* a2s, const void* a2d,
                                                 const int* flags,
                                                 unsigned short* W1frag, float* A1Sf, float* A1Df,
                                                 float* W2f, float* A2Sf, float* A2Df) {
    const bool f32 = flags[0] != 0;
    if (blockIdx.x == 0) {
        auto conv = [&](const void* src, float* dst, int n) {
            if (f32) {
                const float* s = (const float*)src;
                for (int i = threadIdx.x; i < n; i += blockDim.x) dst[i] = s[i];
            } else {
                const unsigned short* s = (const unsigned short*)src;
                for (int i = threadIdx.x; i < n; i += blockDim.x) dst[i] = bf2f(s[i]);
            }
        };
        conv(a1s, A1Sf, HEADS * HID);
        conv(a1d, A1Df, HEADS * HID);
        conv(w2, W2f, D1 * NC);
        conv(a2s, A2Sf, NC);
        conv(a2d, A2Df, NC);
    }
    for (int idx = blockIdx.x * 256 + threadIdx.x; idx < 4 * 16 * 64 * 8; idx += 64 * 256) {
        int wid = idx >> 13, kb = (idx >> 9) & 15, ln = (idx >> 3) & 63, j = idx & 7;
        int k = kb * 32 + (ln >> 4) * 8 + j;
        int n = wid * 16 + (ln & 15);
        unsigned short bits = 0;
        if (k < F_IN) {
            if (f32) bits = f2b(((const float*)w1)[k * D1 + n]);
            else     bits = ((const unsigned short*)w1)[k * D1 + n];
        }
        W1frag[idx] = bits;
    }
}

// ---------------------------------------------------------------- GEMM1 + bucket_scatter (fused grid)
// R16: 256-thread blocks. blocks [0, SBLKS): LDS counting-sort scatter of
// 2048 edges. blocks [SBLKS, SBLKS+GBLKS): MFMA gemm1, 16-row tile (wave w
// owns col group w). 16.6KB LDS -> 8 blocks/CU, 8 barrier domains.
__global__ __launch_bounds__(256, 8) void k_gemm1_scat(const void* xraw, const void* eraw,
                                                       const int* flags,
                                                       const unsigned short* __restrict__ W1frag,
                                                       const float* A1Sf, const float* A1Df,
                                                       unsigned short* __restrict__ h1b,
                                                       float* __restrict__ as1,
                                                       float* __restrict__ ad1,
                                                       int* bucket_cnt, unsigned int* staging) {
    __shared__ unsigned short ldsx[GROWS * LROW];   // 16,640 B
    const int t = threadIdx.x;

    if (blockIdx.x < SBLKS) {
        // ---- scatter branch: LDS counting-sort + coalesced flush ----
        // layout: hist[256] | lbase[256] | gbase[196] | pbk[2048] u8 | pay[2048] u32
        //       = 1024 + 1024 + 784 + 2048 + 8192 = 13,072 B <= 16,640 B
        int* hist  = (int*)ldsx;
        int* lbase = hist + 256;
        int* gbase = lbase + 256;
        unsigned char* pbk = (unsigned char*)(gbase + 196);
        unsigned* pay = (unsigned*)(pbk + 2048);

        const bool e64 = flags[1] != 0;
        const unsigned int* eu = (const unsigned int*)eraw;
        const int e0 = blockIdx.x * SCHUNK;
        const int total = min(SCHUNK, N_EDGES - e0);

        hist[t] = 0;
        __syncthreads();

        int sv[SEPT], dv[SEPT];
#pragma unroll
        for (int k = 0; k < SEPT; k++) {
            int i = e0 + k * 256 + t;
            if (i < N_EDGES) {
                if (e64) { sv[k] = (int)eu[2 * i]; dv[k] = (int)eu[2 * (N_EDGES + i)]; }
                else     { sv[k] = (int)eu[i];     dv[k] = (int)eu[N_EDGES + i]; }
                atomicAdd(&hist[dv[k] >> 9], 1);
            } else dv[k] = -1;
        }
        __syncthreads();

        // inclusive Hillis-Steele scan of hist into lbase (256 threads)
        lbase[t] = hist[t];
        __syncthreads();
        for (int o = 1; o < 256; o <<= 1) {
            int v = (t >= o) ? lbase[t - o] : 0;
            __syncthreads();
            lbase[t] += v;
            __syncthreads();
        }
        // exclusive base + global reservation
        if (t < NB) {
            int c = hist[t];
            int ex = lbase[t] - c;
            int base = c ? atomicAdd(&bucket_cnt[t * CSTR], c) : 0;
            lbase[t] = ex;
            gbase[t] = t * BCAP + base;
        }
        __syncthreads();
        if (t < NB) hist[t] = lbase[t];   // cur tickets
        __syncthreads();

        // LDS ticket scatter (payload bucket-sorted in pay[])
#pragma unroll
        for (int k = 0; k < SEPT; k++) {
            if (dv[k] >= 0) {
                int b = dv[k] >> 9;
                int slot = atomicAdd(&hist[b], 1);
                pay[slot] = (unsigned)sv[k] | ((unsigned)(dv[k] & 511) << 17);
                pbk[slot] = (unsigned char)b;
            }
        }
        __syncthreads();

        // coalesced flush: consecutive j -> contiguous targets within runs
        for (int j = t; j < total; j += 256) {
            int b = pbk[j];
            staging[gbase[b] + (j - lbase[b])] = pay[j];
        }
        return;
    }

    // ---- gemm1 branch (16-row tile, 4 waves; wave w = col group w) ----
    const int r0 = (blockIdx.x - SBLKS) * GROWS;   // 6250*16 = 100000 exactly
    const bool xf32 = flags[0] != 0;
#pragma unroll 4
    for (int it = 0; it < 8; it++) {
        int s = it * 256 + t;
        int row = s >> 7, c4 = s & 127;
        int row_g = r0 + row;
        ushort4 v = make_ushort4(0, 0, 0, 0);
        if (c4 < 125) {
            if (xf32) {
                float4 f = *(const float4*)((const float*)xraw + (size_t)row_g * F_IN + c4 * 4);
                v = make_ushort4(f2b(f.x), f2b(f.y), f2b(f.z), f2b(f.w));
            } else {
                v = *(const ushort4*)((const unsigned short*)xraw + (size_t)row_g * F_IN + c4 * 4);
            }
        }
        *(ushort4*)(ldsx + row * LROW + c4 * 4) = v;
    }
    __syncthreads();

    const int lane = t & 63;
    const int wid = __builtin_amdgcn_readfirstlane(t >> 6);   // 0..3 = col group
    const int m = lane & 15, q = lane >> 4;
    f32x4 acc = {0.f, 0.f, 0.f, 0.f};
    const unsigned short* wf = W1frag + (size_t)wid * 8192;
    const unsigned short* arow = ldsx + m * LROW + q * 8;
#pragma unroll 4
    for (int kb = 0; kb < 16; kb++) {
        bf16x8 b = *(const bf16x8*)(wf + (kb * 64 + lane) * 8);
        bf16x8 a = *(const bf16x8*)(arow + kb * 32);
        acc = __builtin_amdgcn_mfma_f32_16x16x32_bf16(a, b, acc, 0, 0, 0);
    }
    const int col = wid * 16 + m;
    const float a_s = A1Sf[col], a_d = A1Df[col];
    const int h = 2 * wid + (m >> 3);
#pragma unroll
    for (int reg = 0; reg < 4; reg++) {
        int gr = r0 + q * 4 + reg;
        float vacc = acc[reg];
        h1b[(size_t)gr * D1 + col] = f2b(vacc);
        float ts = vacc * a_s, td = vacc * a_d;
        ts += __shfl_xor(ts, 1, 64); td += __shfl_xor(td, 1, 64);
        ts += __shfl_xor(ts, 2, 64); td += __shfl_xor(td, 2, 64);
        ts += __shfl_xor(ts, 4, 64); td += __shfl_xor(td, 4, 64);
        if ((lane & 7) == 0) {
            as1[gr * HEADS + h] = ts;
            ad1[gr * HEADS + h] = td;
        }
    }
}

// pass 2: scan bucket counts -> CSR bucket bases
__global__ void k_cscan(const int* bucket_cnt, int* cbase, int* off) {
    __shared__ int s[256];
    int t = threadIdx.x;
    s[t] = (t < NB) ? bucket_cnt[t * CSTR] : 0;
    __syncthreads();
    for (int o = 1; o < 256; o <<= 1) {
        int v = (t >= o) ? s[t - o] : 0;
        __syncthreads();
        s[t] += v;
        __syncthreads();
    }
    if (t < NB) cbase[t + 1] = s[t];
    if (t == 0) { cbase[0] = 0; off[N_NODES] = N_EDGES; }
}

// pass 3: per-bucket LDS counters; csr writes confined to ~65KB region
__global__ __launch_bounds__(1024) void k_csr_build(const unsigned int* __restrict__ staging,
                                                    const int* __restrict__ bucket_cnt,
                                                    const int* __restrict__ cbase,
                                                    int* __restrict__ off, int* __restrict__ csr) {
    __shared__ int sdeg[512];
    __shared__ int scur[512];
    const int t = threadIdx.x;
    const int b = blockIdx.x;
    const int n0 = b << 9;
    const int start = b * BCAP;
    const int end = start + bucket_cnt[b * CSTR];
    const int base = cbase[b];
    if (t < 512) sdeg[t] = 0;
    __syncthreads();
    for (int i = start + t; i < end; i += 1024)
        atomicAdd(&sdeg[staging[i] >> 17], 1);
    __syncthreads();
    int d = (t < 512) ? sdeg[t] : 0;
    for (int o = 1; o < 512; o <<= 1) {
        int v = (t < 512 && t >= o) ? sdeg[t - o] : 0;
        __syncthreads();
        if (t < 512) sdeg[t] += v;
        __syncthreads();
    }
    if (t < 512) {
        int excl = sdeg[t] - d;
        if (n0 + t < N_NODES) off[n0 + t] = base + excl;
        scur[t] = base + excl;
    }
    __syncthreads();
    for (int i = start + t; i < end; i += 1024) {
        unsigned v = staging[i];
        int slot = atomicAdd(&scur[v >> 17], 1);
        csr[slot] = (int)(v & 0x1FFFFu);
    }
}

// ---------------------------------------------------------------- layer-1 aggregation + ELU
// R4 structure; R13: 8-wide gather groups (deeper memory ILP, same fmaf order).
__global__ __launch_bounds__(256) void k_agg1(const int* __restrict__ csr,
                                              const int* __restrict__ off,
                                              const unsigned short* __restrict__ h1b,
                                              const float* __restrict__ as1,
                                              const float* __restrict__ ad1,
                                              float* __restrict__ h1e) {
    __shared__ float wlds[4][8 * WSTR];
    const int t = threadIdx.x;
    const int lane = t & 63;
    const int n = (blockIdx.x * blockDim.x + t) >> 6;
    if (n >= N_NODES) return;
    const int beg = off[n], end = off[n + 1];
    const int h0 = lane >> 3;
    float* wl = wlds[(t >> 6) & 3];
    const float* wrow = wl + h0 * WSTR;
    const float* adp = ad1 + n * HEADS;   // wave-uniform -> scalar loads
    float acc = 0.f, dsum = 0.f;
    for (int base = beg; base < end; base += 64) {
        const int cnt = min(64, end - base);
        int sl = 0;
        if (lane < cnt) {
            sl = csr[base + lane];
            const float* ap = as1 + sl * HEADS;
            float4 aa = *(const float4*)(ap);
            float4 ab = *(const float4*)(ap + 4);
            wl[0 * WSTR + lane] = __expf(leaky(aa.x + adp[0]));
            wl[1 * WSTR + lane] = __expf(leaky(aa.y + adp[1]));
            wl[2 * WSTR + lane] = __expf(leaky(aa.z + adp[2]));
            wl[3 * WSTR + lane] = __expf(leaky(aa.w + adp[3]));
            wl[4 * WSTR + lane] = __expf(leaky(ab.x + adp[4]));
            wl[5 * WSTR + lane] = __expf(leaky(ab.y + adp[5]));
            wl[6 * WSTR + lane] = __expf(leaky(ab.z + adp[6]));
            wl[7 * WSTR + lane] = __expf(leaky(ab.w + adp[7]));
        }
        // intra-wave LDS RAW: no barrier needed, just drain the ds_writes
        asm volatile("s_waitcnt lgkmcnt(0)" ::: "memory");
        int j = 0;
        for (; j + 8 <= cnt; j += 8) {
            int s0 = __builtin_amdgcn_readlane(sl, j);
            int s1 = __builtin_amdgcn_readlane(sl, j + 1);
            int s2 = __builtin_amdgcn_readlane(sl, j + 2);
            int s3 = __builtin_amdgcn_readlane(sl, j + 3);
            int s4 = __builtin_amdgcn_readlane(sl, j + 4);
            int s5 = __builtin_amdgcn_readlane(sl, j + 5);
            int s6 = __builtin_amdgcn_readlane(sl, j + 6);
            int s7 = __builtin_amdgcn_readlane(sl, j + 7);
            float4 wa = *(const float4*)(wrow + j);       // ds_read_b128
            float4 wb = *(const float4*)(wrow + j + 4);   // ds_read_b128
            float g0 = bf2f(h1b[(size_t)s0 * D1 + lane]);
            float g1 = bf2f(h1b[(size_t)s1 * D1 + lane]);
            float g2 = bf2f(h1b[(size_t)s2 * D1 + lane]);
            float g3 = bf2f(h1b[(size_t)s3 * D1 + lane]);
            float g4 = bf2f(h1b[(size_t)s4 * D1 + lane]);
            float g5 = bf2f(h1b[(size_t)s5 * D1 + lane]);
            float g6 = bf2f(h1b[(size_t)s6 * D1 + lane]);
            float g7 = bf2f(h1b[(size_t)s7 * D1 + lane]);
            acc = fmaf(wa.x, g0, acc); dsum += wa.x;
            acc = fmaf(wa.y, g1, acc); dsum += wa.y;
            acc = fmaf(wa.z, g2, acc); dsum += wa.z;
            acc = fmaf(wa.w, g3, acc); dsum += wa.w;
            acc = fmaf(wb.x, g4, acc); dsum += wb.x;
            acc = fmaf(wb.y, g5, acc); dsum += wb.y;
            acc = fmaf(wb.z, g6, acc); dsum += wb.z;
            acc = fmaf(wb.w, g7, acc); dsum += wb.w;
        }
        for (; j + 4 <= cnt; j += 4) {
            int s0 = __builtin_amdgcn_readlane(sl, j);
            int s1 = __builtin_amdgcn_readlane(sl, j + 1);
            int s2 = __builtin_amdgcn_readlane(sl, j + 2);
            int s3 = __builtin_amdgcn_readlane(sl, j + 3);
            float4 wv = *(const float4*)(wrow + j);
            float g0 = bf2f(h1b[(size_t)s0 * D1 + lane]);
            float g1 = bf2f(h1b[(size_t)s1 * D1 + lane]);
            float g2 = bf2f(h1b[(size_t)s2 * D1 + lane]);
            float g3 = bf2f(h1b[(size_t)s3 * D1 + lane]);
            acc = fmaf(wv.x, g0, acc); dsum += wv.x;
            acc = fmaf(wv.y, g1, acc); dsum += wv.y;
            acc = fmaf(wv.z, g2, acc); dsum += wv.z;
            acc = fmaf(wv.w, g3, acc); dsum += wv.w;
        }
        for (; j < cnt; j++) {
            int s = __builtin_amdgcn_readlane(sl, j);
            float w = wrow[j];
            acc = fmaf(w, bf2f(h1b[(size_t)s * D1 + lane]), acc);
            dsum += w;
        }
    }
    float v = acc / (dsum + 1e-16f);
    float o = v > 0.f ? v : (__expf(v) - 1.f);   // ELU
    h1e[(size_t)n * D1 + lane] = o;
}

// ---------------------------------------------------------------- GEMM2 (thread=row)
// R7: writes line-aligned padded rows h2p[row][64] (cols 41..63 unused).
__global__ __launch_bounds__(256) void k_gemm2(const float* __restrict__ h1e,
                                               const float* __restrict__ W2f,
                                               const float* __restrict__ A2Sf,
                                               const float* __restrict__ A2Df,
                                               unsigned short* __restrict__ h2p,
                                               float* __restrict__ as2,
                                               float* __restrict__ ad2) {
    const int row = blockIdx.x * blockDim.x + threadIdx.x;
    if (row >= N_NODES) return;
    float acc[NC];
#pragma unroll
    for (int c = 0; c < NC; c++) acc[c] = 0.f;
    const float* xr = h1e + (size_t)row * D1;
    for (int k = 0; k < D1; k += 4) {
        float4 hv = *(const float4*)(xr + k);
#pragma unroll
        for (int c = 0; c < NC; c++) {
            acc[c] = fmaf(hv.x, W2f[(k + 0) * NC + c], acc[c]);
            acc[c] = fmaf(hv.y, W2f[(k + 1) * NC + c], acc[c]);
            acc[c] = fmaf(hv.z, W2f[(k + 2) * NC + c], acc[c]);
            acc[c] = fmaf(hv.w, W2f[(k + 3) * NC + c], acc[c]);
        }
    }
    float ts = 0.f, td = 0.f;
#pragma unroll
    for (int c = 0; c < NC; c++) {
        h2p[(size_t)row * NCP + c] = f2b(acc[c]);
        ts = fmaf(acc[c], A2Sf[c], ts);
        td = fmaf(acc[c], A2Df[c], td);
    }
    as2[row] = ts;
    ad2[row] = td;
}

// ---------------------------------------------------------------- layer-2 aggregation + log_softmax
// R4 structure; padded h2p rows; R13 8-wide groups; R15 dsum wave-reduce.
__global__ __launch_bounds__(256) void k_agg2(const int* __restrict__ csr,
                                              const int* __restrict__ off,
                                              const unsigned short* __restrict__ h2p,
                                              const float* __restrict__ as2,
                                              const float* __restrict__ ad2,
                                              const int* flags, void* out) {
    const int lane = threadIdx.x & 63;
    const int n = (blockIdx.x * blockDim.x + threadIdx.x) >> 6;
    if (n >= N_NODES) return;
    const int beg = off[n], end = off[n + 1];
    const float ad = ad2[n];
    const bool act = lane < NC;
    const int cl = act ? lane : 0;
    float acc = 0.f, dsum = 0.f;
    for (int base = beg; base < end; base += 64) {
        const int cnt = min(64, end - base);
        int idx = min(base + lane, N_EDGES - 1);
        int sl = csr[idx];
        float w = __expf(leaky(as2[sl] + ad));
        // R15: per-round dsum via masked wave reduction (replaces per-edge adds)
        float ws = (lane < cnt) ? w : 0.f;
#pragma unroll
        for (int o = 1; o < 64; o <<= 1) ws += __shfl_xor(ws, o, 64);
        dsum += ws;
        int j = 0;
        for (; j + 8 <= cnt; j += 8) {
            int s0 = __builtin_amdgcn_readlane(sl, j);
            int s1 = __builtin_amdgcn_readlane(sl, j + 1);
            int s2 = __builtin_amdgcn_readlane(sl, j + 2);
            int s3 = __builtin_amdgcn_readlane(sl, j + 3);
            int s4 = __builtin_amdgcn_readlane(sl, j + 4);
            int s5 = __builtin_amdgcn_readlane(sl, j + 5);
            int s6 = __builtin_amdgcn_readlane(sl, j + 6);
            int s7 = __builtin_amdgcn_readlane(sl, j + 7);
            float w0 = readlane_f(w, j);
            float w1 = readlane_f(w, j + 1);
            float w2 = readlane_f(w, j + 2);
            float w3 = readlane_f(w, j + 3);
            float w4 = readlane_f(w, j + 4);
            float w5 = readlane_f(w, j + 5);
            float w6 = readlane_f(w, j + 6);
            float w7 = readlane_f(w, j + 7);
            float g0 = bf2f(h2p[(size_t)s0 * NCP + cl]);
            float g1 = bf2f(h2p[(size_t)s1 * NCP + cl]);
            float g2 = bf2f(h2p[(size_t)s2 * NCP + cl]);
            float g3 = bf2f(h2p[(size_t)s3 * NCP + cl]);
            float g4 = bf2f(h2p[(size_t)s4 * NCP + cl]);
            float g5 = bf2f(h2p[(size_t)s5 * NCP + cl]);
            float g6 = bf2f(h2p[(size_t)s6 * NCP + cl]);
            float g7 = bf2f(h2p[(size_t)s7 * NCP + cl]);
            acc = fmaf(w0, g0, acc);
            acc = fmaf(w1, g1, acc);
            acc = fmaf(w2, g2, acc);
            acc = fmaf(w3, g3, acc);
            acc = fmaf(w4, g4, acc);
            acc = fmaf(w5, g5, acc);
            acc = fmaf(w6, g6, acc);
            acc = fmaf(w7, g7, acc);
        }
        for (; j + 4 <= cnt; j += 4) {
            int s0 = __builtin_amdgcn_readlane(sl, j);
            int s1 = __builtin_amdgcn_readlane(sl, j + 1);
            int s2 = __builtin_amdgcn_readlane(sl, j + 2);
            int s3 = __builtin_amdgcn_readlane(sl, j + 3);
            float w0 = readlane_f(w, j);
            float w1 = readlane_f(w, j + 1);
            float w2 = readlane_f(w, j + 2);
            float w3 = readlane_f(w, j + 3);
            float g0 = bf2f(h2p[(size_t)s0 * NCP + cl]);
            float g1 = bf2f(h2p[(size_t)s1 * NCP + cl]);
            float g2 = bf2f(h2p[(size_t)s2 * NCP + cl]);
            float g3 = bf2f(h2p[(size_t)s3 * NCP + cl]);
            acc = fmaf(w0, g0, acc);
            acc = fmaf(w1, g1, acc);
            acc = fmaf(w2, g2, acc);
            acc = fmaf(w3, g3, acc);
        }
        for (; j < cnt; j++) {
            int s = __builtin_amdgcn_readlane(sl, j);
            float wj = readlane_f(w, j);
            acc = fmaf(wj, bf2f(h2p[(size_t)s * NCP + cl]), acc);
        }
    }
    float val = acc / (dsum + 1e-16f);
    float v = act ? val : -INFINITY;
    float m = v;
#pragma unroll
    for (int o = 1; o < 64; o <<= 1) m = fmaxf(m, __shfl_xor(m, o, 64));
    float ex = act ? __expf(val - m) : 0.f;
#pragma unroll
    for (int o = 1; o < 64; o <<= 1) ex += __shfl_xor(ex, o, 64);
    float res = val - m - __logf(ex);
    if (act) {
        if (flags[0])
            ((float*)out)[(size_t)n * NC + lane] = res;
        else
            ((__hip_bfloat16*)out)[(size_t)n * NC + lane] = __float2bfloat16(res);
    }
}

// ---------------------------------------------------------------- host
extern "C" void kernel_launch(void* const* d_in, const int* in_sizes, int n_in,
                              void* d_out, int out_size, void* d_ws, size_t ws_size,
                              hipStream_t stream) {
    char* p = (char*)d_ws;
    auto alloc = [&](size_t bytes) -> void* {
        void* r = (void*)p;
        p += (bytes + 255) & ~(size_t)255;
        return r;
    };
    int* flags  = (int*)alloc(16);
    unsigned short* W1frag = (unsigned short*)alloc(4 * 16 * 64 * 8 * 2);
    float* A1Sf = (float*)alloc(HEADS * HID * 4);
    float* A1Df = (float*)alloc(HEADS * HID * 4);
    float* W2f  = (float*)alloc((size_t)D1 * NC * 4);
    float* A2Sf = (float*)alloc(NC * 4);
    float* A2Df = (float*)alloc(NC * 4);
    unsigned short* h1b = (unsigned short*)alloc((size_t)N_NODES * D1 * 2);
    float* as1  = (float*)alloc((size_t)N_NODES * HEADS * 4);
    float* ad1  = (float*)alloc((size_t)N_NODES * HEADS * 4);
    float* h1e  = (float*)alloc((size_t)N_NODES * D1 * 4);
    unsigned short* h2p = (unsigned short*)alloc((size_t)N_NODES * NCP * 2);   // padded rows
    float* as2  = (float*)alloc((size_t)N_NODES * 4);
    float* ad2  = (float*)alloc((size_t)N_NODES * 4);
    int* off    = (int*)alloc((size_t)(N_NODES + 1) * 4);
    int* csr    = (int*)alloc((size_t)N_EDGES * 4);
    int* bucket_cnt = (int*)alloc((size_t)NB * CSTR * 4);   // 64B-padded counters
    int* cbase      = (int*)alloc((size_t)(NB + 1) * 4);
    // staging aliases h1e (dead until agg1 writes h1e): 16.06 MB <= 25.6 MB
    unsigned int* staging = (unsigned int*)h1e;

    hipMemsetAsync(bucket_cnt, 0, (size_t)NB * CSTR * 4, stream);

    k_detect<<<1, 64, 0, stream>>>(d_in[0], d_in[1], flags);
    k_convert<<<64, 256, 0, stream>>>(d_in[2], d_in[3], d_in[4], d_in[5], d_in[6], d_in[7],
                                      flags, W1frag, A1Sf, A1Df, W2f, A2Sf, A2Df);
    k_gemm1_scat<<<SBLKS + GBLKS, 256, 0, stream>>>(d_in[0], d_in[1], flags, W1frag,
                                                    A1Sf, A1Df, h1b, as1, ad1,
                                                    bucket_cnt, staging);
    k_cscan<<<1, 256, 0, stream>>>(bucket_cnt, cbase, off);
    k_csr_build<<<NB, 1024, 0, stream>>>(staging, bucket_cnt, cbase, off, csr);

    k_agg1<<<25000, 256, 0, stream>>>(csr, off, h1b, as1, ad1, h1e);
    k_gemm2<<<391, 256, 0, stream>>>(h1e, W2f, A2Sf, A2Df, h2p, as2, ad2);
    k_agg2<<<25000, 256, 0, stream>>>(csr, off, h2p, as2, ad2, flags, d_out);
}

// Round 14
// 574.757 us; speedup vs baseline: 1.0334x; 1.0334x over previous
//
#include <hip/hip_runtime.h>
#include <hip/hip_bf16.h>
#include <math.h>

// GAT 2-layer inference on MI355X.
// R1: gemm1 lane=row + LDS tile.  R2: bucketed CSR; fused agg; gemm2 thread=row.
// R3: gemm1 MFMA bf16; bf16 gather tables.
// R4: agg lane-parallel weight precompute + readlane broadcast (VALU fix).
// R5: gemm1 32-row tile x 512thr (occupancy fix); detect/convert split.
// R6 (REVERTED): sliced XCD-pinned aggs -- 3x instruction overhead.
// R7: h2 rows padded to 128B; scatter fused into gemm1 grid.
// R8 (REVERTED): 196->782 buckets doubled staging write-amp.
// R9 (REVERTED): direct ticket scatter -- random global atomics+stores ~10x cost.
// R10 (NEUTRAL): bucket_cnt line padding.
// R11: scatter branch LDS counting-sort + coalesced flush (WRITE 62->39MB). [593.3]
// R12 (REVERTED): deg histogram via 3.2M random global atomics (+100MB HBM).
// R13: agg gather groups 4->8 wide (latency-bound gathers). [577.5us BEST]
// R14 (REVERTED): 16-wide groups (VGPR pressure) bundled with dsum hoist.
// R15 (NEUTRAL): agg2 dsum hoist alone -- kept.
// R16 (REVERTED): 256thr/8blk fused kernel -- +8MB write-amp, no latency win.
// R17: Hillis-Steele LDS scans -> wave-level shfl_up scans. Scatter branch:
//      17 barriers -> 2 per block (x782 blocks); csr_build: 19 -> 2 (x196
//      blocks, 16 waves parked each). e64 edge loads -> int2 (half the
//      load instructions, same lines).

#define DEV __device__ __forceinline__

constexpr int N_NODES = 100000;
constexpr int N_EDGES = 3200000;
constexpr int F_IN    = 500;
constexpr int HEADS   = 8;
constexpr int HID     = 8;
constexpr int D1      = HEADS * HID;   // 64
constexpr int NC      = 41;
constexpr int NCP     = 64;            // padded h2 row stride (128B line-aligned)

// bucketed CSR build
constexpr int NB    = 196;     // buckets of 512 nodes (dst >> 9)
constexpr int BCAP  = 20480;   // staging capacity per bucket (avg 16327)
constexpr int CSTR  = 16;      // bucket_cnt stride in ints (64B line per counter)
constexpr int SEPT  = 8;       // edges per thread in scatter branch (512 thr)
constexpr int SCHUNK = 512 * SEPT;   // 4096 edges per scatter block
constexpr int SBLKS = (N_EDGES + SCHUNK - 1) / SCHUNK;   // 782

// gemm1 MFMA tile
constexpr int GROWS = 32;      // rows per block
constexpr int LROW  = 520;     // LDS row stride in bf16
constexpr int GBLKS = N_NODES / GROWS;   // 3125

// agg1 per-wave weight tile: 8 heads x 64 edges, stride 68 floats
constexpr int WSTR = 68;

typedef __attribute__((ext_vector_type(8))) short bf16x8;
typedef __attribute__((ext_vector_type(4))) float f32x4;

DEV float bf2f(unsigned short u) {
    return __uint_as_float(((unsigned int)u) << 16);
}
DEV unsigned short f2b(float f) {   // RNE f32 -> bf16 bits
    unsigned int u = __float_as_uint(f);
    unsigned int r = (u + 0x7FFFu + ((u >> 16) & 1u)) >> 16;
    return (unsigned short)r;
}
DEV float leaky(float e) { return e > 0.f ? e : 0.2f * e; }
DEV float readlane_f(float v, int l) {
    return __uint_as_float((unsigned int)__builtin_amdgcn_readlane((int)__float_as_uint(v), l));
}
// wave-inclusive scan of int via shfl_up (no barriers)
DEV int wave_iscan(int v, int lane) {
#pragma unroll
    for (int o = 1; o < 64; o <<= 1) {
        int u = __shfl_up(v, o, 64);
        if (lane >= o) v += u;
    }
    return v;
}

// ---------------------------------------------------------------- detect (1 wave)
__global__ void k_detect(const void* xraw, const void* eraw, int* flags) {
    const int lane = threadIdx.x & 63;
    const unsigned short* xu = (const unsigned short*)xraw;
    unsigned short v = xu[2 * lane];
    int e = (v >> 7) & 0xFF;
    int valid = (e == 0 || (e >= 90 && e <= 150)) ? 1 : 0;
    unsigned long long vm = __ballot(valid);
    const unsigned int* eu = (const unsigned int*)eraw;
    unsigned long long zm = __ballot(eu[2 * lane + 1] == 0u);
    if (lane == 0) {
        flags[0] = (__popcll(vm) < 56) ? 1 : 0;   // x is f32
        flags[1] = (__popcll(zm) == 64) ? 1 : 0;  // edge_index is i64
    }
}

// ---------------------------------------------------------------- convert weights (parallel)
__global__ __launch_bounds__(256) void k_convert(const void* w1, const void* a1s, const void* a1d,
                                                 const void* w2, const void* a2s, const void* a2d,
                                                 const int* flags,
                                                 unsigned short* W1frag, float* A1Sf, float* A1Df,
                                                 float* W2f, float* A2Sf, float* A2Df) {
    const bool f32 = flags[0] != 0;
    if (blockIdx.x == 0) {
        auto conv = [&](const void* src, float* dst, int n) {
            if (f32) {
                const float* s = (const float*)src;
                for (int i = threadIdx.x; i < n; i += blockDim.x) dst[i] = s[i];
            } else {
                const unsigned short* s = (const unsigned short*)src;
                for (int i = threadIdx.x; i < n; i += blockDim.x) dst[i] = bf2f(s[i]);
            }
        };
        conv(a1s, A1Sf, HEADS * HID);
        conv(a1d, A1Df, HEADS * HID);
        conv(w2, W2f, D1 * NC);
        conv(a2s, A2Sf, NC);
        conv(a2d, A2Df, NC);
    }
    for (int idx = blockIdx.x * 256 + threadIdx.x; idx < 4 * 16 * 64 * 8; idx += 64 * 256) {
        int wid = idx >> 13, kb = (idx >> 9) & 15, ln = (idx >> 3) & 63, j = idx & 7;
        int k = kb * 32 + (ln >> 4) * 8 + j;
        int n = wid * 16 + (ln & 15);
        unsigned short bits = 0;
        if (k < F_IN) {
            if (f32) bits = f2b(((const float*)w1)[k * D1 + n]);
            else     bits = ((const unsigned short*)w1)[k * D1 + n];
        }
        W1frag[idx] = bits;
    }
}

// ---------------------------------------------------------------- GEMM1 + bucket_scatter (fused grid)
// blocks [0, SBLKS): CSR bucket scatter via block-local LDS counting-sort.
// blocks [SBLKS, SBLKS+GBLKS): MFMA gemm1, 32-row tile.
__global__ __launch_bounds__(512, 8) void k_gemm1_scat(const void* xraw, const void* eraw,
                                                       const int* flags,
                                                       const unsigned short* __restrict__ W1frag,
                                                       const float* A1Sf, const float* A1Df,
                                                       unsigned short* __restrict__ h1b,
                                                       float* __restrict__ as1,
                                                       float* __restrict__ ad1,
                                                       int* bucket_cnt, unsigned int* staging) {
    __shared__ unsigned short ldsx[GROWS * LROW];
    const int t = threadIdx.x;

    if (blockIdx.x < SBLKS) {
        // ---- scatter branch: LDS counting-sort + coalesced flush ----
        int* hist  = (int*)ldsx;
        int* lbase = hist + 256;
        int* gbase = lbase + 256;
        int* wsum  = gbase + 196;                       // [8] wave totals
        unsigned char* pbk = (unsigned char*)(wsum + 8);
        unsigned* pay = (unsigned*)(pbk + 4096);

        const bool e64 = flags[1] != 0;
        const unsigned int* eu = (const unsigned int*)eraw;
        const int e0 = blockIdx.x * SCHUNK;
        const int total = min(SCHUNK, N_EDGES - e0);
        const int lane = t & 63, wv = t >> 6;

        for (int i = t; i < 256; i += 512) hist[i] = 0;
        __syncthreads();

        int sv[SEPT], dv[SEPT];
#pragma unroll
        for (int k = 0; k < SEPT; k++) {
            int i = e0 + k * 512 + t;
            if (i < N_EDGES) {
                if (e64) {
                    int2 ps = ((const int2*)eu)[i];
                    int2 pd = ((const int2*)eu)[N_EDGES + i];
                    sv[k] = ps.x; dv[k] = pd.x;
                } else {
                    sv[k] = (int)eu[i];
                    dv[k] = (int)eu[N_EDGES + i];
                }
                atomicAdd(&hist[dv[k] >> 9], 1);
            } else dv[k] = -1;
        }
        __syncthreads();

        // R17: shfl-based inclusive scan of hist[0..255] (2 barriers total)
        int val = (t < 256) ? hist[t] : 0;
        val = wave_iscan(val, lane);
        if (lane == 63) wsum[wv] = val;
        __syncthreads();
        int pre = 0;
#pragma unroll
        for (int i = 0; i < 4; i++) pre += (i < wv) ? wsum[i] : 0;
        if (t < 256) lbase[t] = val + pre;   // inclusive scan
        __syncthreads();

        // exclusive base + global reservation
        if (t < NB) {
            int c = hist[t];
            int ex = lbase[t] - c;
            int base = c ? atomicAdd(&bucket_cnt[t * CSTR], c) : 0;
            lbase[t] = ex;
            gbase[t] = t * BCAP + base;
        }
        __syncthreads();
        if (t < NB) hist[t] = lbase[t];   // cur tickets
        __syncthreads();

        // LDS ticket scatter (payload bucket-sorted in pay[])
#pragma unroll
        for (int k = 0; k < SEPT; k++) {
            if (dv[k] >= 0) {
                int b = dv[k] >> 9;
                int slot = atomicAdd(&hist[b], 1);
                pay[slot] = (unsigned)sv[k] | ((unsigned)(dv[k] & 511) << 17);
                pbk[slot] = (unsigned char)b;
            }
        }
        __syncthreads();

        // coalesced flush: consecutive j -> contiguous targets within runs
        for (int j = t; j < total; j += 512) {
            int b = pbk[j];
            staging[gbase[b] + (j - lbase[b])] = pay[j];
        }
        return;
    }

    // ---- gemm1 branch ----
    const int r0 = (blockIdx.x - SBLKS) * GROWS;   // 3125*32 = 100000 exactly
    const bool xf32 = flags[0] != 0;
#pragma unroll 4
    for (int it = 0; it < 8; it++) {
        int s = it * 512 + t;
        int row = s >> 7, c4 = s & 127;
        int row_g = r0 + row;
        ushort4 v = make_ushort4(0, 0, 0, 0);
        if (c4 < 125) {
            if (xf32) {
                float4 f = *(const float4*)((const float*)xraw + (size_t)row_g * F_IN + c4 * 4);
                v = make_ushort4(f2b(f.x), f2b(f.y), f2b(f.z), f2b(f.w));
            } else {
                v = *(const ushort4*)((const unsigned short*)xraw + (size_t)row_g * F_IN + c4 * 4);
            }
        }
        *(ushort4*)(ldsx + row * LROW + c4 * 4) = v;
    }
    __syncthreads();

    const int lane = t & 63;
    const int w = t >> 6;
    const int wid = __builtin_amdgcn_readfirstlane(w & 3);
    const int mb  = __builtin_amdgcn_readfirstlane(w >> 2);
    const int m = lane & 15, q = lane >> 4;
    f32x4 acc = {0.f, 0.f, 0.f, 0.f};
    const unsigned short* wf = W1frag + (size_t)wid * 8192;
    const unsigned short* arow = ldsx + (mb * 16 + m) * LROW + q * 8;
#pragma unroll 4
    for (int kb = 0; kb < 16; kb++) {
        bf16x8 b = *(const bf16x8*)(wf + (kb * 64 + lane) * 8);
        bf16x8 a = *(const bf16x8*)(arow + kb * 32);
        acc = __builtin_amdgcn_mfma_f32_16x16x32_bf16(a, b, acc, 0, 0, 0);
    }
    const int col = wid * 16 + m;
    const float a_s = A1Sf[col], a_d = A1Df[col];
    const int h = 2 * wid + (m >> 3);
#pragma unroll
    for (int reg = 0; reg < 4; reg++) {
        int gr = r0 + mb * 16 + q * 4 + reg;
        float vacc = acc[reg];
        h1b[(size_t)gr * D1 + col] = f2b(vacc);
        float ts = vacc * a_s, td = vacc * a_d;
        ts += __shfl_xor(ts, 1, 64); td += __shfl_xor(td, 1, 64);
        ts += __shfl_xor(ts, 2, 64); td += __shfl_xor(td, 2, 64);
        ts += __shfl_xor(ts, 4, 64); td += __shfl_xor(td, 4, 64);
        if ((lane & 7) == 0) {
            as1[gr * HEADS + h] = ts;
            ad1[gr * HEADS + h] = td;
        }
    }
}

// pass 2: scan bucket counts -> CSR bucket bases
__global__ void k_cscan(const int* bucket_cnt, int* cbase, int* off) {
    __shared__ int s[256];
    int t = threadIdx.x;
    s[t] = (t < NB) ? bucket_cnt[t * CSTR] : 0;
    __syncthreads();
    for (int o = 1; o < 256; o <<= 1) {
        int v = (t >= o) ? s[t - o] : 0;
        __syncthreads();
        s[t] += v;
        __syncthreads();
    }
    if (t < NB) cbase[t + 1] = s[t];
    if (t == 0) { cbase[0] = 0; off[N_NODES] = N_EDGES; }
}

// pass 3: per-bucket LDS counters; csr writes confined to ~65KB region
// R17: shfl-based scan (2 barriers instead of 19).
__global__ __launch_bounds__(1024) void k_csr_build(const unsigned int* __restrict__ staging,
                                                    const int* __restrict__ bucket_cnt,
                                                    const int* __restrict__ cbase,
                                                    int* __restrict__ off, int* __restrict__ csr) {
    __shared__ int sdeg[512];
    __shared__ int scur[512];
    __shared__ int wsum[16];
    const int t = threadIdx.x;
    const int b = blockIdx.x;
    const int n0 = b << 9;
    const int start = b * BCAP;
    const int end = start + bucket_cnt[b * CSTR];
    const int base = cbase[b];
    const int lane = t & 63, wv = t >> 6;
    if (t < 512) sdeg[t] = 0;
    __syncthreads();
    for (int i = start + t; i < end; i += 1024)
        atomicAdd(&sdeg[staging[i] >> 17], 1);
    __syncthreads();
    int d = (t < 512) ? sdeg[t] : 0;
    int val = wave_iscan(d, lane);
    if (lane == 63) wsum[wv] = val;
    __syncthreads();
    int pre = 0;
#pragma unroll
    for (int i = 0; i < 8; i++) pre += (i < wv) ? wsum[i] : 0;
    if (t < 512) {
        int excl = val + pre - d;   // exclusive scan
        if (n0 + t < N_NODES) off[n0 + t] = base + excl;
        scur[t] = base + excl;
    }
    __syncthreads();
    for (int i = start + t; i < end; i += 1024) {
        unsigned v = staging[i];
        int slot = atomicAdd(&scur[v >> 17], 1);
        csr[slot] = (int)(v & 0x1FFFFu);
    }
}

// ---------------------------------------------------------------- layer-1 aggregation + ELU
// R4 structure; R13: 8-wide gather groups (deeper memory ILP, same fmaf order).
__global__ __launch_bounds__(256) void k_agg1(const int* __restrict__ csr,
                                              const int* __restrict__ off,
                                              const unsigned short* __restrict__ h1b,
                                              const float* __restrict__ as1,
                                              const float* __restrict__ ad1,
                                              float* __restrict__ h1e) {
    __shared__ float wlds[4][8 * WSTR];
    const int t = threadIdx.x;
    const int lane = t & 63;
    const int n = (blockIdx.x * blockDim.x + t) >> 6;
    if (n >= N_NODES) return;
    const int beg = off[n], end = off[n + 1];
    const int h0 = lane >> 3;
    float* wl = wlds[(t >> 6) & 3];
    const float* wrow = wl + h0 * WSTR;
    const float* adp = ad1 + n * HEADS;   // wave-uniform -> scalar loads
    float acc = 0.f, dsum = 0.f;
    for (int base = beg; base < end; base += 64) {
        const int cnt = min(64, end - base);
        int sl = 0;
        if (lane < cnt) {
            sl = csr[base + lane];
            const float* ap = as1 + sl * HEADS;
            float4 aa = *(const float4*)(ap);
            float4 ab = *(const float4*)(ap + 4);
            wl[0 * WSTR + lane] = __expf(leaky(aa.x + adp[0]));
            wl[1 * WSTR + lane] = __expf(leaky(aa.y + adp[1]));
            wl[2 * WSTR + lane] = __expf(leaky(aa.z + adp[2]));
            wl[3 * WSTR + lane] = __expf(leaky(aa.w + adp[3]));
            wl[4 * WSTR + lane] = __expf(leaky(ab.x + adp[4]));
            wl[5 * WSTR + lane] = __expf(leaky(ab.y + adp[5]));
            wl[6 * WSTR + lane] = __expf(leaky(ab.z + adp[6]));
            wl[7 * WSTR + lane] = __expf(leaky(ab.w + adp[7]));
        }
        // intra-wave LDS RAW: no barrier needed, just drain the ds_writes
        asm volatile("s_waitcnt lgkmcnt(0)" ::: "memory");
        int j = 0;
        for (; j + 8 <= cnt; j += 8) {
            int s0 = __builtin_amdgcn_readlane(sl, j);
            int s1 = __builtin_amdgcn_readlane(sl, j + 1);
            int s2 = __builtin_amdgcn_readlane(sl, j + 2);
            int s3 = __builtin_amdgcn_readlane(sl, j + 3);
            int s4 = __builtin_amdgcn_readlane(sl, j + 4);
            int s5 = __builtin_amdgcn_readlane(sl, j + 5);
            int s6 = __builtin_amdgcn_readlane(sl, j + 6);
            int s7 = __builtin_amdgcn_readlane(sl, j + 7);
            float4 wa = *(const float4*)(wrow + j);       // ds_read_b128
            float4 wb = *(const float4*)(wrow + j + 4);   // ds_read_b128
            float g0 = bf2f(h1b[(size_t)s0 * D1 + lane]);
            float g1 = bf2f(h1b[(size_t)s1 * D1 + lane]);
            float g2 = bf2f(h1b[(size_t)s2 * D1 + lane]);
            float g3 = bf2f(h1b[(size_t)s3 * D1 + lane]);
            float g4 = bf2f(h1b[(size_t)s4 * D1 + lane]);
            float g5 = bf2f(h1b[(size_t)s5 * D1 + lane]);
            float g6 = bf2f(h1b[(size_t)s6 * D1 + lane]);
            float g7 = bf2f(h1b[(size_t)s7 * D1 + lane]);
            acc = fmaf(wa.x, g0, acc); dsum += wa.x;
            acc = fmaf(wa.y, g1, acc); dsum += wa.y;
            acc = fmaf(wa.z, g2, acc); dsum += wa.z;
            acc = fmaf(wa.w, g3, acc); dsum += wa.w;
            acc = fmaf(wb.x, g4, acc); dsum += wb.x;
            acc = fmaf(wb.y, g5, acc); dsum += wb.y;
            acc = fmaf(wb.z, g6, acc); dsum += wb.z;
            acc = fmaf(wb.w, g7, acc); dsum += wb.w;
        }
        for (; j + 4 <= cnt; j += 4) {
            int s0 = __builtin_amdgcn_readlane(sl, j);
            int s1 = __builtin_amdgcn_readlane(sl, j + 1);
            int s2 = __builtin_amdgcn_readlane(sl, j + 2);
            int s3 = __builtin_amdgcn_readlane(sl, j + 3);
            float4 wv = *(const float4*)(wrow + j);
            float g0 = bf2f(h1b[(size_t)s0 * D1 + lane]);
            float g1 = bf2f(h1b[(size_t)s1 * D1 + lane]);
            float g2 = bf2f(h1b[(size_t)s2 * D1 + lane]);
            float g3 = bf2f(h1b[(size_t)s3 * D1 + lane]);
            acc = fmaf(wv.x, g0, acc); dsum += wv.x;
            acc = fmaf(wv.y, g1, acc); dsum += wv.y;
            acc = fmaf(wv.z, g2, acc); dsum += wv.z;
            acc = fmaf(wv.w, g3, acc); dsum += wv.w;
        }
        for (; j < cnt; j++) {
            int s = __builtin_amdgcn_readlane(sl, j);
            float w = wrow[j];
            acc = fmaf(w, bf2f(h1b[(size_t)s * D1 + lane]), acc);
            dsum += w;
        }
    }
    float v = acc / (dsum + 1e-16f);
    float o = v > 0.f ? v : (__expf(v) - 1.f);   // ELU
    h1e[(size_t)n * D1 + lane] = o;
}

// ---------------------------------------------------------------- GEMM2 (thread=row)
// R7: writes line-aligned padded rows h2p[row][64] (cols 41..63 unused).
__global__ __launch_bounds__(256) void k_gemm2(const float* __restrict__ h1e,
                                               const float* __restrict__ W2f,
                                               const float* __restrict__ A2Sf,
                                               const float* __restrict__ A2Df,
                                               unsigned short* __restrict__ h2p,
                                               float* __restrict__ as2,
                                               float* __restrict__ ad2) {
    const int row = blockIdx.x * blockDim.x + threadIdx.x;
    if (row >= N_NODES) return;
    float acc[NC];
#pragma unroll
    for (int c = 0; c < NC; c++) acc[c] = 0.f;
    const float* xr = h1e + (size_t)row * D1;
    for (int k = 0; k < D1; k += 4) {
        float4 hv = *(const float4*)(xr + k);
#pragma unroll
        for (int c = 0; c < NC; c++) {
            acc[c] = fmaf(hv.x, W2f[(k + 0) * NC + c], acc[c]);
            acc[c] = fmaf(hv.y, W2f[(k + 1) * NC + c], acc[c]);
            acc[c] = fmaf(hv.z, W2f[(k + 2) * NC + c], acc[c]);
            acc[c] = fmaf(hv.w, W2f[(k + 3) * NC + c], acc[c]);
        }
    }
    float ts = 0.f, td = 0.f;
#pragma unroll
    for (int c = 0; c < NC; c++) {
        h2p[(size_t)row * NCP + c] = f2b(acc[c]);
        ts = fmaf(acc[c], A2Sf[c], ts);
        td = fmaf(acc[c], A2Df[c], td);
    }
    as2[row] = ts;
    ad2[row] = td;
}

// ---------------------------------------------------------------- layer-2 aggregation + log_softmax
// R4 structure; padded h2p rows; R13 8-wide groups; R15 dsum wave-reduce.
__global__ __launch_bounds__(256) void k_agg2(const int* __restrict__ csr,
                                              const int* __restrict__ off,
                                              const unsigned short* __restrict__ h2p,
                                              const float* __restrict__ as2,
                                              const float* __restrict__ ad2,
                                              const int* flags, void* out) {
    const int lane = threadIdx.x & 63;
    const int n = (blockIdx.x * blockDim.x + threadIdx.x) >> 6;
    if (n >= N_NODES) return;
    const int beg = off[n], end = off[n + 1];
    const float ad = ad2[n];
    const bool act = lane < NC;
    const int cl = act ? lane : 0;
    float acc = 0.f, dsum = 0.f;
    for (int base = beg; base < end; base += 64) {
        const int cnt = min(64, end - base);
        int idx = min(base + lane, N_EDGES - 1);
        int sl = csr[idx];
        float w = __expf(leaky(as2[sl] + ad));
        // R15: per-round dsum via masked wave reduction
        float ws = (lane < cnt) ? w : 0.f;
#pragma unroll
        for (int o = 1; o < 64; o <<= 1) ws += __shfl_xor(ws, o, 64);
        dsum += ws;
        int j = 0;
        for (; j + 8 <= cnt; j += 8) {
            int s0 = __builtin_amdgcn_readlane(sl, j);
            int s1 = __builtin_amdgcn_readlane(sl, j + 1);
            int s2 = __builtin_amdgcn_readlane(sl, j + 2);
            int s3 = __builtin_amdgcn_readlane(sl, j + 3);
            int s4 = __builtin_amdgcn_readlane(sl, j + 4);
            int s5 = __builtin_amdgcn_readlane(sl, j + 5);
            int s6 = __builtin_amdgcn_readlane(sl, j + 6);
            int s7 = __builtin_amdgcn_readlane(sl, j + 7);
            float w0 = readlane_f(w, j);
            float w1 = readlane_f(w, j + 1);
            float w2 = readlane_f(w, j + 2);
            float w3 = readlane_f(w, j + 3);
            float w4 = readlane_f(w, j + 4);
            float w5 = readlane_f(w, j + 5);
            float w6 = readlane_f(w, j + 6);
            float w7 = readlane_f(w, j + 7);
            float g0 = bf2f(h2p[(size_t)s0 * NCP + cl]);
            float g1 = bf2f(h2p[(size_t)s1 * NCP + cl]);
            float g2 = bf2f(h2p[(size_t)s2 * NCP + cl]);
            float g3 = bf2f(h2p[(size_t)s3 * NCP + cl]);
            float g4 = bf2f(h2p[(size_t)s4 * NCP + cl]);
            float g5 = bf2f(h2p[(size_t)s5 * NCP + cl]);
            float g6 = bf2f(h2p[(size_t)s6 * NCP + cl]);
            float g7 = bf2f(h2p[(size_t)s7 * NCP + cl]);
            acc = fmaf(w0, g0, acc);
            acc = fmaf(w1, g1, acc);
            acc = fmaf(w2, g2, acc);
            acc = fmaf(w3, g3, acc);
            acc = fmaf(w4, g4, acc);
            acc = fmaf(w5, g5, acc);
            acc = fmaf(w6, g6, acc);
            acc = fmaf(w7, g7, acc);
        }
        for (; j + 4 <= cnt; j += 4) {
            int s0 = __builtin_amdgcn_readlane(sl, j);
            int s1 = __builtin_amdgcn_readlane(sl, j + 1);
            int s2 = __builtin_amdgcn_readlane(sl, j + 2);
            int s3 = __builtin_amdgcn_readlane(sl, j + 3);
            float w0 = readlane_f(w, j);
            float w1 = readlane_f(w, j + 1);
            float w2 = readlane_f(w, j + 2);
            float w3 = readlane_f(w, j + 3);
            float g0 = bf2f(h2p[(size_t)s0 * NCP + cl]);
            float g1 = bf2f(h2p[(size_t)s1 * NCP + cl]);
            float g2 = bf2f(h2p[(size_t)s2 * NCP + cl]);
            float g3 = bf2f(h2p[(size_t)s3 * NCP + cl]);
            acc = fmaf(w0, g0, acc);
            acc = fmaf(w1, g1, acc);
            acc = fmaf(w2, g2, acc);
            acc = fmaf(w3, g3, acc);
        }
        for (; j < cnt; j++) {
            int s = __builtin_amdgcn_readlane(sl, j);
            float wj = readlane_f(w, j);
            acc = fmaf(wj, bf2f(h2p[(size_t)s * NCP + cl]), acc);
        }
    }
    float val = acc / (dsum + 1e-16f);
    float v = act ? val : -INFINITY;
    float m = v;
#pragma unroll
    for (int o = 1; o < 64; o <<= 1) m = fmaxf(m, __shfl_xor(m, o, 64));
    float ex = act ? __expf(val - m) : 0.f;
#pragma unroll
    for (int o = 1; o < 64; o <<= 1) ex += __shfl_xor(ex, o, 64);
    float res = val - m - __logf(ex);
    if (act) {
        if (flags[0])
            ((float*)out)[(size_t)n * NC + lane] = res;
        else
            ((__hip_bfloat16*)out)[(size_t)n * NC + lane] = __float2bfloat16(res);
    }
}

// ---------------------------------------------------------------- host
extern "C" void kernel_launch(void* const* d_in, const int* in_sizes, int n_in,
                              void* d_out, int out_size, void* d_ws, size_t ws_size,
                              hipStream_t stream) {
    char* p = (char*)d_ws;
    auto alloc = [&](size_t bytes) -> void* {
        void* r = (void*)p;
        p += (bytes + 255) & ~(size_t)255;
        return r;
    };
    int* flags  = (int*)alloc(16);
    unsigned short* W1frag = (unsigned short*)alloc(4 * 16 * 64 * 8 * 2);
    float* A1Sf = (float*)alloc(HEADS * HID * 4);
    float* A1Df = (float*)alloc(HEADS * HID * 4);
    float* W2f  = (float*)alloc((size_t)D1 * NC * 4);
    float* A2Sf = (float*)alloc(NC * 4);
    float* A2Df = (float*)alloc(NC * 4);
    unsigned short* h1b = (unsigned short*)alloc((size_t)N_NODES * D1 * 2);
    float* as1  = (float*)alloc((size_t)N_NODES * HEADS * 4);
    float* ad1  = (float*)alloc((size_t)N_NODES * HEADS * 4);
    float* h1e  = (float*)alloc((size_t)N_NODES * D1 * 4);
    unsigned short* h2p = (unsigned short*)alloc((size_t)N_NODES * NCP * 2);   // padded rows
    float* as2  = (float*)alloc((size_t)N_NODES * 4);
    float* ad2  = (float*)alloc((size_t)N_NODES * 4);
    int* off    = (int*)alloc((size_t)(N_NODES + 1) * 4);
    int* csr    = (int*)alloc((size_t)N_EDGES * 4);
    int* bucket_cnt = (int*)alloc((size_t)NB * CSTR * 4);   // 64B-padded counters
    int* cbase      = (int*)alloc((size_t)(NB + 1) * 4);
    // staging aliases h1e (dead until agg1 writes h1e): 16.06 MB <= 25.6 MB
    unsigned int* staging = (unsigned int*)h1e;

    hipMemsetAsync(bucket_cnt, 0, (size_t)NB * CSTR * 4, stream);

    k_detect<<<1, 64, 0, stream>>>(d_in[0], d_in[1], flags);
    k_convert<<<64, 256, 0, stream>>>(d_in[2], d_in[3], d_in[4], d_in[5], d_in[6], d_in[7],
                                      flags, W1frag, A1Sf, A1Df, W2f, A2Sf, A2Df);
    k_gemm1_scat<<<SBLKS + GBLKS, 512, 0, stream>>>(d_in[0], d_in[1], flags, W1frag,
                                                    A1Sf, A1Df, h1b, as1, ad1,
                                                    bucket_cnt, staging);
    k_cscan<<<1, 256, 0, stream>>>(bucket_cnt, cbase, off);
    k_csr_build<<<NB, 1024, 0, stream>>>(staging, bucket_cnt, cbase, off, csr);

    k_agg1<<<25000, 256, 0, stream>>>(csr, off, h1b, as1, ad1, h1e);
    k_gemm2<<<391, 256, 0, stream>>>(h1e, W2f, A2Sf, A2Df, h2p, as2, ad2);
    k_agg2<<<25000, 256, 0, stream>>>(csr, off, h2p, as2, ad2, flags, d_out);
}